// Round 6
// baseline (549.479 us; speedup 1.0000x reference)
//
#include <hip/hip_runtime.h>
#include <stdint.h>

typedef unsigned int uint;
typedef unsigned short ushort;
typedef unsigned char uchar;
typedef __attribute__((ext_vector_type(8))) short bf16x8;
typedef __attribute__((ext_vector_type(4))) float f32x4;

__device__ __forceinline__ ushort f2bf(float f) {
  uint u = __builtin_bit_cast(uint, f);
  return (ushort)((u + 0x7FFFu + ((u >> 16) & 1u)) >> 16);
}

// ---------------------------------------------------------------------------
// Mask element width: esz stays nonzero if every sampled 4-byte word is in
// {0,1,0x3F800000} (int32/float32 masks); byte masks fail with certainty.
__global__ __launch_bounds__(256) void k_detect(
    const uint* __restrict__ mp, const uint* __restrict__ ms,
    const uint* __restrict__ mt, int* __restrict__ esz) {
  int bid = blockIdx.x;  // 192 blocks: 3 masks x 64 chunks
  const uint* m = (bid < 64) ? mp : (bid < 128) ? ms : mt;
  uint v = m[(size_t)(bid & 63) * 65521 + threadIdx.x];
  if (!(v == 0u || v == 1u || v == 0x3F800000u)) atomicAnd(esz, 0);
}

// ---------------------------------------------------------------------------
// Fused-weight stage 1: T1 = W_space @ W_mix[0:128], T2 = W_same @ W_mix[128:256]
__global__ __launch_bounds__(256) void k_fuse1(
    const float* __restrict__ Ws, const float* __restrict__ Wsame,
    const float* __restrict__ Wm, float* __restrict__ T1, float* __restrict__ T2) {
  int idx = blockIdx.x * 256 + threadIdx.x;
  if (idx >= 81920) return;
  int r = idx >> 7, n = idx & 127;
  float s = 0.f;
  if (r < 384) {
    for (int c = 0; c < 128; ++c) s += Ws[r * 128 + c] * Wm[c * 128 + n];
    T1[r * 128 + n] = s;
  } else {
    int rr = r - 384;
    for (int c = 0; c < 128; ++c) s += Wsame[rr * 128 + c] * Wm[(128 + c) * 128 + n];
    T2[rr * 128 + n] = s;
  }
}

// ---------------------------------------------------------------------------
// Stage 2: UT[y][n][k] (bf16) for y=0:origin 1:pred 2:succ 3:same, plus
// cvec[0..3][n] bias vectors (c0 includes all constant paths).
__global__ __launch_bounds__(256) void k_fuse2(
    const float* __restrict__ We, const float* __restrict__ be,
    const float* __restrict__ bs, const float* __restrict__ bsame,
    const float* __restrict__ bm_, const float* __restrict__ Wm,
    const float* __restrict__ T1, const float* __restrict__ T2,
    ushort* __restrict__ UT, float* __restrict__ cvec) {
  int idx = blockIdx.x * 256 + threadIdx.x;
  if (idx < 65536) {
    int y = idx >> 14, n = (idx >> 7) & 127, k = idx & 127;
    float s = 0.f;
    if (y == 0)
      for (int m = 0; m < 128; ++m)
        s += We[k * 512 + m] * (T1[(128 + m) * 128 + n] + T2[m * 128 + n]);
    else if (y == 1)
      for (int m = 0; m < 128; ++m) s += We[k * 512 + 128 + m] * T1[m * 128 + n];
    else if (y == 2)
      for (int m = 0; m < 128; ++m) s += We[k * 512 + 256 + m] * T1[(256 + m) * 128 + n];
    else
      for (int m = 0; m < 128; ++m) s += We[k * 512 + 384 + m] * T2[(128 + m) * 128 + n];
    UT[((size_t)y * 128 + n) * 128 + k] = f2bf(s);
  } else if (idx < 66048) {
    int cid = idx - 65536, cv = cid >> 7, n = cid & 127;
    float s = 0.f;
    if (cv == 0) {
      for (int m = 0; m < 128; ++m)
        s += be[m] * (T1[(128 + m) * 128 + n] + T2[m * 128 + n]);
      for (int c = 0; c < 128; ++c) s += bs[c] * Wm[c * 128 + n];
      for (int c = 0; c < 128; ++c) s += bsame[c] * Wm[(128 + c) * 128 + n];
      s += bm_[n];
    } else if (cv == 1) {
      for (int m = 0; m < 128; ++m) s += be[128 + m] * T1[m * 128 + n];
    } else if (cv == 2) {
      for (int m = 0; m < 128; ++m) s += be[256 + m] * T1[(256 + m) * 128 + n];
    } else {
      for (int m = 0; m < 128; ++m) s += be[384 + m] * T2[(128 + m) * 128 + n];
    }
    cvec[cv * 128 + n] = s;
  }
}

// ---------------------------------------------------------------------------
// Encoder: feat(f32) @ UT[y]. y=0 -> out = origin + c0 (natural row order);
// y=1..3 -> e'_mid in MFMA-B-fragment order with a within-tile COLUMN
// PERMUTATION (bit-shuffle cl->u) matching k_mm's amplification-free mask
// loads: u = cl with bits rearranged (u5=cl5, u4u3=cl3cl2, u2=cl4, u1u0=cl1cl0).
__global__ __launch_bounds__(256) void k_enc(
    const float* __restrict__ feat, const ushort* __restrict__ UT,
    const float* __restrict__ cvec, float* __restrict__ out,
    ushort* __restrict__ eT0, ushort* __restrict__ eT1, ushort* __restrict__ eT2) {
  __shared__ ushort As[64 * 72];
  __shared__ ushort Bs[128 * 72];
  __shared__ ushort stage[8192];
  const int t = threadIdx.x;
  const int gm0 = blockIdx.x * 64;
  const int y = blockIdx.y;
  const int lane = t & 63, wave = t >> 6;
  const int m0w = (wave >> 1) * 32, n0w = (wave & 1) * 64;
  const int quad = lane >> 4, lr = lane & 15;
  const int am = t >> 2, aq = t & 3;
  const int bn = t >> 1, bh = t & 1;
  f32x4 acc[2][4] = {};
  for (int k0 = 0; k0 < 128; k0 += 64) {
    const float* asrc = feat + (size_t)(gm0 + am) * 128 + k0 + aq * 16;
    float4 f0 = *(const float4*)asrc;
    float4 f1 = *(const float4*)(asrc + 4);
    float4 f2 = *(const float4*)(asrc + 8);
    float4 f3 = *(const float4*)(asrc + 12);
    ushort h[16];
    h[0] = f2bf(f0.x); h[1] = f2bf(f0.y); h[2] = f2bf(f0.z); h[3] = f2bf(f0.w);
    h[4] = f2bf(f1.x); h[5] = f2bf(f1.y); h[6] = f2bf(f1.z); h[7] = f2bf(f1.w);
    h[8] = f2bf(f2.x); h[9] = f2bf(f2.y); h[10] = f2bf(f2.z); h[11] = f2bf(f2.w);
    h[12] = f2bf(f3.x); h[13] = f2bf(f3.y); h[14] = f2bf(f3.z); h[15] = f2bf(f3.w);
    const ushort* bsrc = UT + ((size_t)y * 128 + bn) * 128 + k0 + bh * 32;
    bf16x8 bv0 = *(const bf16x8*)bsrc;
    bf16x8 bv1 = *(const bf16x8*)(bsrc + 8);
    bf16x8 bv2 = *(const bf16x8*)(bsrc + 16);
    bf16x8 bv3 = *(const bf16x8*)(bsrc + 24);
    *(bf16x8*)&As[am * 72 + aq * 16] = *(bf16x8*)&h[0];
    *(bf16x8*)&As[am * 72 + aq * 16 + 8] = *(bf16x8*)&h[8];
    *(bf16x8*)&Bs[bn * 72 + bh * 32] = bv0;
    *(bf16x8*)&Bs[bn * 72 + bh * 32 + 8] = bv1;
    *(bf16x8*)&Bs[bn * 72 + bh * 32 + 16] = bv2;
    *(bf16x8*)&Bs[bn * 72 + bh * 32 + 24] = bv3;
    __syncthreads();
#pragma unroll
    for (int kc = 0; kc < 2; ++kc) {
      bf16x8 a[2], b[4];
#pragma unroll
      for (int i = 0; i < 2; ++i)
        a[i] = *(const bf16x8*)&As[(m0w + i * 16 + lr) * 72 + kc * 32 + quad * 8];
#pragma unroll
      for (int j = 0; j < 4; ++j)
        b[j] = *(const bf16x8*)&Bs[(n0w + j * 16 + lr) * 72 + kc * 32 + quad * 8];
#pragma unroll
      for (int i = 0; i < 2; ++i)
#pragma unroll
        for (int j = 0; j < 4; ++j)
          acc[i][j] = __builtin_amdgcn_mfma_f32_16x16x32_bf16(a[i], b[j], acc[i][j], 0, 0, 0);
    }
    __syncthreads();
  }
  if (y == 0) {
#pragma unroll
    for (int i = 0; i < 2; ++i)
#pragma unroll
      for (int j = 0; j < 4; ++j)
#pragma unroll
        for (int r = 0; r < 4; ++r) {
          int m = gm0 + m0w + i * 16 + quad * 4 + r;
          int n = n0w + j * 16 + lr;
          out[(size_t)m * 128 + n] = acc[i][j][r] + cvec[n];
        }
  } else {
#pragma unroll
    for (int i = 0; i < 2; ++i)
#pragma unroll
      for (int j = 0; j < 4; ++j)
#pragma unroll
        for (int r = 0; r < 4; ++r) {
          int cl = m0w + i * 16 + quad * 4 + r;  // local feature-row (column)
          int u = (cl & 32) + (((cl >> 2) & 3) * 8) + ((cl >> 4) & 1) * 4 + (cl & 3);
          int n = n0w + j * 16 + lr;
          int kc = u >> 5, qd = (u >> 3) & 3, e = u & 7;
          stage[((((n >> 4) * 2 + kc) * 4 + qd) * 16 + (n & 15)) * 8 + e] =
              f2bf(acc[i][j][r]);
        }
    __syncthreads();
    ushort* eT = (y == 1) ? eT0 : (y == 2) ? eT1 : eT2;
    ushort* dst = eT + ((size_t)(gm0 >> 11) * 32 + ((gm0 >> 6) & 31)) * 8192 + t * 32;
    const ushort* src = stage + t * 32;
#pragma unroll
    for (int p = 0; p < 4; ++p)
      *(bf16x8*)(dst + p * 8) = *(const bf16x8*)(src + p * 8);
  }
}

// ---------------------------------------------------------------------------
// Fused masked-mean GEMM: raw int32 masks read DIRECTLY as A-fragments.
// Column permutation (see k_enc) makes every A-load instruction cover 16
// complete 64B lines: lane(quad,lr) row(lr) reads 16B at byte quad*16 (h=0)
// and 64+quad*16 (h=1) within the row's 128B it-chunk -> zero request
// amplification. Fragment: e<4 <- h0 ints, e>=4 <- h1 ints. Degree counted
// in-block. Depth-2 prefetch, statically-named register buffers (R4 lesson).
__global__ __launch_bounds__(256, 3) void k_mm(
    const void* __restrict__ mp, const void* __restrict__ ms,
    const void* __restrict__ mt, const ushort* __restrict__ eT0,
    const ushort* __restrict__ eT1, const ushort* __restrict__ eT2,
    const float* __restrict__ cvec, float* __restrict__ P0,
    float* __restrict__ P1, float* __restrict__ P2,
    const int* __restrict__ esz_p) {
  __shared__ uint degs[64];
  const int t = threadIdx.x;
  const int id = blockIdx.x;
  const int xcd = id & 7, q = id >> 3;
  const int mtile = q & 31, gg = xcd * 3 + (q >> 5);
  const int b = gg & 7, mid = gg >> 3;
  const void* mask = (mid == 0) ? mp : (mid == 1) ? ms : mt;
  const ushort* eT = (mid == 0) ? eT0 : (mid == 1) ? eT1 : eT2;
  float* Pm = (mid == 0) ? P0 : (mid == 1) ? P1 : P2;
  const float* cm = cvec + (mid + 1) * 128;
  const bool is4 = (*esz_p != 0);
  if (t < 64) degs[t] = 0;
  __syncthreads();

  const int lane = t & 63, wave = t >> 6;
  const int m0w = (wave >> 1) * 32, n0w = (wave & 1) * 64;
  const int quad = lane >> 4, lr = lane & 15;
  const int jb = n0w >> 4;
  const size_t rowbase = (size_t)b * 2048 + mtile * 64;
  const size_t r0 = rowbase + m0w + lr;
  const size_t r1 = r0 + 16;
  const ushort* bbase = eT + (size_t)b * 32 * 8192 + quad * 128 + lr * 8;

  f32x4 acc[2][4] = {};
  int cnt0 = 0, cnt1 = 0;

  if (is4) {
    const uint* A0b = (const uint*)mask + r0 * 2048 + quad * 4;
    const uint* A1b = (const uint*)mask + r1 * 2048 + quad * 4;
    uint4 p00, p01, p10, p11;  // buf0: [row][half]
    uint4 q00, q01, q10, q11;  // buf1
    bf16x8 pB[4], qB[4];

#define MM_LOAD4(IT, A00, A01, A10, A11, PB)                                  \
  do {                                                                        \
    int it_ = (IT);                                                           \
    if (it_ > 63) it_ = 63;                                                   \
    const uint* p0_ = A0b + it_ * 32;                                         \
    const uint* p1_ = A1b + it_ * 32;                                         \
    A00 = *(const uint4*)p0_;                                                 \
    A01 = *(const uint4*)(p0_ + 16);                                          \
    A10 = *(const uint4*)p1_;                                                 \
    A11 = *(const uint4*)(p1_ + 16);                                          \
    const ushort* bp_ = bbase + (it_ >> 1) * 8192 + (it_ & 1) * 512;          \
    _Pragma("unroll")                                                         \
    for (int j_ = 0; j_ < 4; ++j_)                                            \
      PB[j_] = *(const bf16x8*)(bp_ + (jb + j_) * 1024);                      \
  } while (0)

#define MM_STEP4(A00, A01, A10, A11, PB)                                      \
  do {                                                                        \
    union { bf16x8 v; uint u[4]; } af0, af1;                                  \
    af0.u[0] = (A00.x ? 0x3F80u : 0u) | (A00.y ? 0x3F800000u : 0u);           \
    af0.u[1] = (A00.z ? 0x3F80u : 0u) | (A00.w ? 0x3F800000u : 0u);           \
    af0.u[2] = (A01.x ? 0x3F80u : 0u) | (A01.y ? 0x3F800000u : 0u);           \
    af0.u[3] = (A01.z ? 0x3F80u : 0u) | (A01.w ? 0x3F800000u : 0u);           \
    cnt0 += (A00.x != 0u) + (A00.y != 0u) + (A00.z != 0u) + (A00.w != 0u) +   \
            (A01.x != 0u) + (A01.y != 0u) + (A01.z != 0u) + (A01.w != 0u);    \
    af1.u[0] = (A10.x ? 0x3F80u : 0u) | (A10.y ? 0x3F800000u : 0u);           \
    af1.u[1] = (A10.z ? 0x3F80u : 0u) | (A10.w ? 0x3F800000u : 0u);           \
    af1.u[2] = (A11.x ? 0x3F80u : 0u) | (A11.y ? 0x3F800000u : 0u);           \
    af1.u[3] = (A11.z ? 0x3F80u : 0u) | (A11.w ? 0x3F800000u : 0u);           \
    cnt1 += (A10.x != 0u) + (A10.y != 0u) + (A10.z != 0u) + (A10.w != 0u) +   \
            (A11.x != 0u) + (A11.y != 0u) + (A11.z != 0u) + (A11.w != 0u);    \
    _Pragma("unroll")                                                         \
    for (int j_ = 0; j_ < 4; ++j_) {                                          \
      acc[0][j_] = __builtin_amdgcn_mfma_f32_16x16x32_bf16(af0.v, PB[j_],     \
                                                           acc[0][j_], 0, 0, 0);\
      acc[1][j_] = __builtin_amdgcn_mfma_f32_16x16x32_bf16(af1.v, PB[j_],     \
                                                           acc[1][j_], 0, 0, 0);\
    }                                                                         \
  } while (0)

    MM_LOAD4(0, p00, p01, p10, p11, pB);
    MM_LOAD4(1, q00, q01, q10, q11, qB);
    for (int it2 = 0; it2 < 32; ++it2) {
      MM_STEP4(p00, p01, p10, p11, pB);
      MM_LOAD4(2 * it2 + 2, p00, p01, p10, p11, pB);
      MM_STEP4(q00, q01, q10, q11, qB);
      MM_LOAD4(2 * it2 + 3, q00, q01, q10, q11, qB);
    }
#undef MM_LOAD4
#undef MM_STEP4
  } else {
    // byte masks: correct but simple path (real inputs are int32 per detect)
    const uchar* B0b = (const uchar*)mask + r0 * 2048 + quad * 4;
    const uchar* B1b = (const uchar*)mask + r1 * 2048 + quad * 4;
    for (int it = 0; it < 64; ++it) {
      uint lo0 = *(const uint*)(B0b + it * 32);
      uint hi0 = *(const uint*)(B0b + it * 32 + 16);
      uint lo1 = *(const uint*)(B1b + it * 32);
      uint hi1 = *(const uint*)(B1b + it * 32 + 16);
      bf16x8 pb[4];
      const ushort* bp = bbase + (it >> 1) * 8192 + (it & 1) * 512;
#pragma unroll
      for (int j = 0; j < 4; ++j) pb[j] = *(const bf16x8*)(bp + (jb + j) * 1024);
      union { bf16x8 v; uint u[4]; } af0, af1;
      af0.u[0] = ((lo0 & 0xFFu) ? 0x3F80u : 0u) | ((lo0 & 0xFF00u) ? 0x3F800000u : 0u);
      af0.u[1] = ((lo0 & 0xFF0000u) ? 0x3F80u : 0u) | ((lo0 & 0xFF000000u) ? 0x3F800000u : 0u);
      af0.u[2] = ((hi0 & 0xFFu) ? 0x3F80u : 0u) | ((hi0 & 0xFF00u) ? 0x3F800000u : 0u);
      af0.u[3] = ((hi0 & 0xFF0000u) ? 0x3F80u : 0u) | ((hi0 & 0xFF000000u) ? 0x3F800000u : 0u);
      af1.u[0] = ((lo1 & 0xFFu) ? 0x3F80u : 0u) | ((lo1 & 0xFF00u) ? 0x3F800000u : 0u);
      af1.u[1] = ((lo1 & 0xFF0000u) ? 0x3F80u : 0u) | ((lo1 & 0xFF000000u) ? 0x3F800000u : 0u);
      af1.u[2] = ((hi1 & 0xFFu) ? 0x3F80u : 0u) | ((hi1 & 0xFF00u) ? 0x3F800000u : 0u);
      af1.u[3] = ((hi1 & 0xFF0000u) ? 0x3F80u : 0u) | ((hi1 & 0xFF000000u) ? 0x3F800000u : 0u);
      cnt0 += ((lo0 & 0xFFu) != 0u) + ((lo0 & 0xFF00u) != 0u) +
              ((lo0 & 0xFF0000u) != 0u) + ((lo0 & 0xFF000000u) != 0u) +
              ((hi0 & 0xFFu) != 0u) + ((hi0 & 0xFF00u) != 0u) +
              ((hi0 & 0xFF0000u) != 0u) + ((hi0 & 0xFF000000u) != 0u);
      cnt1 += ((lo1 & 0xFFu) != 0u) + ((lo1 & 0xFF00u) != 0u) +
              ((lo1 & 0xFF0000u) != 0u) + ((lo1 & 0xFF000000u) != 0u) +
              ((hi1 & 0xFFu) != 0u) + ((hi1 & 0xFF00u) != 0u) +
              ((hi1 & 0xFF0000u) != 0u) + ((hi1 & 0xFF000000u) != 0u);
#pragma unroll
      for (int j = 0; j < 4; ++j) {
        acc[0][j] = __builtin_amdgcn_mfma_f32_16x16x32_bf16(af0.v, pb[j], acc[0][j], 0, 0, 0);
        acc[1][j] = __builtin_amdgcn_mfma_f32_16x16x32_bf16(af1.v, pb[j], acc[1][j], 0, 0, 0);
      }
    }
  }

  // Degrees: n0w==0 waves only -> each (row, col) counted exactly once.
  if ((wave & 1) == 0) {
    atomicAdd(&degs[m0w + lr], (uint)cnt0);
    atomicAdd(&degs[m0w + 16 + lr], (uint)cnt1);
  }
  __syncthreads();

  float cmv[4];
#pragma unroll
  for (int j = 0; j < 4; ++j) cmv[j] = cm[n0w + j * 16 + lr];
#pragma unroll
  for (int i = 0; i < 2; ++i)
#pragma unroll
    for (int r = 0; r < 4; ++r) {
      const int ml = m0w + i * 16 + quad * 4 + r;
      const size_t row = rowbase + ml;
      const uint d = degs[ml];
      const float iv = 1.0f / (float)(d > 0u ? d : 1u);
      const float id_ = (d > 0u) ? 1.0f : 0.0f;
#pragma unroll
      for (int j = 0; j < 4; ++j) {
        const int n = n0w + j * 16 + lr;
        Pm[row * 128 + n] = acc[i][j][r] * iv + id_ * cmv[j];
      }
    }
}

// ---------------------------------------------------------------------------
// Final merge: out(base) += P0 + P1 + P2. Pure streaming.
__global__ __launch_bounds__(256) void k_add(
    float4* __restrict__ out, const float4* __restrict__ P0,
    const float4* __restrict__ P1, const float4* __restrict__ P2) {
  const int i = blockIdx.x * 256 + threadIdx.x;  // 524288 float4s
  float4 o = out[i];
  const float4 a = P0[i], b = P1[i], c = P2[i];
  o.x += a.x + b.x + c.x;
  o.y += a.y + b.y + c.y;
  o.z += a.z + b.z + c.z;
  o.w += a.w + b.w + c.w;
  out[i] = o;
}

// ---------------------------------------------------------------------------
extern "C" void kernel_launch(void* const* d_in, const int* in_sizes, int n_in,
                              void* d_out, int out_size, void* d_ws,
                              size_t ws_size, hipStream_t stream) {
  const float* features = (const float*)d_in[0];
  const void* pred = d_in[1];
  const void* succ = d_in[2];
  const void* same = d_in[3];
  const float* W_enc = (const float*)d_in[4];
  const float* b_enc = (const float*)d_in[5];
  const float* W_space = (const float*)d_in[6];
  const float* b_space = (const float*)d_in[7];
  const float* W_same = (const float*)d_in[8];
  const float* b_same = (const float*)d_in[9];
  const float* W_mix = (const float*)d_in[10];
  const float* b_mix = (const float*)d_in[11];
  float* out = (float*)d_out;

  char* wsb = (char*)d_ws;
  ushort* UT = (ushort*)wsb;                          // 128 KB
  float* cvec = (float*)(wsb + 131072);               // 2 KB
  float* T1 = (float*)(wsb + 133120);                 // 192 KB
  float* T2 = (float*)(wsb + 329728);                 // 128 KB
  ushort* eT0 = (ushort*)(wsb + 460800);              // 4 MB each
  ushort* eT1 = (ushort*)(wsb + 460800 + 4194304);
  ushort* eT2 = (ushort*)(wsb + 460800 + 8388608);
  float* P0 = (float*)(wsb + 13043712);               // 8 MB each
  float* P1 = (float*)(wsb + 13043712 + 8388608);
  float* P2 = (float*)(wsb + 13043712 + 16777216);
  int* esz = (int*)(wsb + 38209536);

  hipMemsetAsync(esz, 1, 4, stream);
  k_detect<<<192, 256, 0, stream>>>((const uint*)pred, (const uint*)succ,
                                    (const uint*)same, esz);
  k_fuse1<<<320, 256, 0, stream>>>(W_space, W_same, W_mix, T1, T2);
  k_fuse2<<<258, 256, 0, stream>>>(W_enc, b_enc, b_space, b_same, b_mix, W_mix,
                                   T1, T2, UT, cvec);
  k_enc<<<dim3(256, 4), 256, 0, stream>>>(features, UT, cvec, out, eT0, eT1, eT2);
  k_mm<<<768, 256, 0, stream>>>(pred, succ, same, eT0, eT1, eT2, cvec,
                                P0, P1, P2, esz);
  k_add<<<2048, 256, 0, stream>>>((float4*)out, (const float4*)P0,
                                  (const float4*)P1, (const float4*)P2);
}

// Round 7
// 458.384 us; speedup vs baseline: 1.1987x; 1.1987x over previous
//
#include <hip/hip_runtime.h>
#include <stdint.h>

typedef unsigned int uint;
typedef unsigned long long ull;
typedef unsigned short ushort;
typedef unsigned char uchar;
typedef __attribute__((ext_vector_type(8))) short bf16x8;
typedef __attribute__((ext_vector_type(4))) float f32x4;

__device__ __forceinline__ ushort f2bf(float f) {
  uint u = __builtin_bit_cast(uint, f);
  return (ushort)((u + 0x7FFFu + ((u >> 16) & 1u)) >> 16);
}

// ---------------------------------------------------------------------------
// PERMUTED COLUMN ORDER (shared contract between k_pack, k_enc, k_mm):
// permuted index u = q*256 + e*64 + h*32 + j  <->  original column
// c = q*256 + (h*32+j)*4 + e.  Bitmap word w = u>>5 holds bits j of the
// ballot over columns with (q = w>>3, e = (w>>1)&3, h = w&1).  eT tiles are
// written so fragment K-position u matches; masked-mean is permutation-
// invariant over columns, so results are exact.
// ---------------------------------------------------------------------------

// Mask element width: esz stays nonzero if every sampled 4-byte word is in
// {0,1,0x3F800000} (int32/float32 masks); byte masks fail with certainty.
__global__ __launch_bounds__(256) void k_detect(
    const uint* __restrict__ mp, const uint* __restrict__ ms,
    const uint* __restrict__ mt, int* __restrict__ esz) {
  int bid = blockIdx.x;  // 192 blocks: 3 masks x 64 chunks
  const uint* m = (bid < 64) ? mp : (bid < 128) ? ms : mt;
  uint v = m[(size_t)(bid & 63) * 65521 + threadIdx.x];
  if (!(v == 0u || v == 1u || v == 0x3F800000u)) atomicAnd(esz, 0);
}

// ---------------------------------------------------------------------------
// Streaming mask compression, AMPLIFICATION-FREE: every load instruction
// covers contiguous full cache lines (int32 path: lane i reads 16B at
// base+q*1024+i*16 -> 1KB/instr).  Ballots assemble the permuted bitmap.
__global__ __launch_bounds__(256) void k_pack(
    const void* __restrict__ mp, const void* __restrict__ ms,
    const void* __restrict__ mt, uint* __restrict__ bm,
    float* __restrict__ inv, float* __restrict__ ind,
    const int* __restrict__ esz_p) {
  const int gid = blockIdx.x * 4 + (threadIdx.x >> 6);  // 49152 rows
  const int lane = threadIdx.x & 63;
  const int mid = gid >> 14;
  const int row = gid & 16383;
  const void* mask = (mid == 0) ? mp : (mid == 1) ? ms : mt;
  const bool is4 = (*esz_p != 0);
  uint myword = 0;
  int cnt = 0;
  if (is4) {
    const uint* base = (const uint*)mask + (size_t)row * 2048;
    const int qsel = lane >> 3;
    const int e0 = (lane >> 1) & 1, e1 = (lane >> 2) & 1;
    const int hs = (lane & 1) * 32;
#pragma unroll
    for (int q = 0; q < 8; ++q) {
      uint4 v = *(const uint4*)(base + q * 256 + lane * 4);
      ull b0 = __ballot(v.x != 0u);
      ull b1 = __ballot(v.y != 0u);
      ull b2 = __ballot(v.z != 0u);
      ull b3 = __ballot(v.w != 0u);
      cnt += __popcll(b0) + __popcll(b1) + __popcll(b2) + __popcll(b3);
      ull s0 = e0 ? b1 : b0;
      ull s1 = e0 ? b3 : b2;
      ull sel = e1 ? s1 : s0;
      if (qsel == q) myword = (uint)(sel >> hs);
    }
    if (lane == 0) {
      inv[gid] = 1.0f / (float)(cnt > 0 ? cnt : 1);
      ind[gid] = (cnt > 0) ? 1.0f : 0.0f;
    }
  } else {
    // byte path: lane owns bitmap word w=lane; reads its 128 contiguous bytes
    const uchar* base = (const uchar*)mask + (size_t)row * 2048 +
                        (lane >> 3) * 256 + (lane & 1) * 128;
    const int e = (lane >> 1) & 3;
#pragma unroll
    for (int p = 0; p < 8; ++p) {
      uint4 v = *(const uint4*)(base + p * 16);
      uint a[4] = {v.x, v.y, v.z, v.w};
#pragma unroll
      for (int x = 0; x < 4; ++x) {
        uint bit = (((a[x] >> (8 * e)) & 0xFFu) != 0u) ? 1u : 0u;
        myword |= bit << (p * 4 + x);
      }
    }
    int c = __popc(myword);
#pragma unroll
    for (int off = 1; off < 64; off <<= 1) c += __shfl_xor(c, off, 64);
    if (lane == 0) {
      inv[gid] = 1.0f / (float)(c > 0 ? c : 1);
      ind[gid] = (c > 0) ? 1.0f : 0.0f;
    }
  }
  bm[(size_t)gid * 64 + lane] = myword;
}

// ---------------------------------------------------------------------------
// Fused-weight stage 1: T1 = W_space @ W_mix[0:128], T2 = W_same @ W_mix[128:256]
__global__ __launch_bounds__(256) void k_fuse1(
    const float* __restrict__ Ws, const float* __restrict__ Wsame,
    const float* __restrict__ Wm, float* __restrict__ T1, float* __restrict__ T2) {
  int idx = blockIdx.x * 256 + threadIdx.x;
  if (idx >= 81920) return;
  int r = idx >> 7, n = idx & 127;
  float s = 0.f;
  if (r < 384) {
    for (int c = 0; c < 128; ++c) s += Ws[r * 128 + c] * Wm[c * 128 + n];
    T1[r * 128 + n] = s;
  } else {
    int rr = r - 384;
    for (int c = 0; c < 128; ++c) s += Wsame[rr * 128 + c] * Wm[(128 + c) * 128 + n];
    T2[rr * 128 + n] = s;
  }
}

// ---------------------------------------------------------------------------
// Stage 2: UTf[y] (bf16, MFMA B-FRAGMENT order) for y=0:origin 1:pred 2:succ
// 3:same, plus cvec[0..3][n] (c0 includes all constant paths).
__global__ __launch_bounds__(256) void k_fuse2(
    const float* __restrict__ We, const float* __restrict__ be,
    const float* __restrict__ bs, const float* __restrict__ bsame,
    const float* __restrict__ bm_, const float* __restrict__ Wm,
    const float* __restrict__ T1, const float* __restrict__ T2,
    ushort* __restrict__ UTf, float* __restrict__ cvec) {
  int idx = blockIdx.x * 256 + threadIdx.x;
  if (idx < 65536) {
    int y = idx >> 14, n = (idx >> 7) & 127, k = idx & 127;
    float s = 0.f;
    if (y == 0)
      for (int m = 0; m < 128; ++m)
        s += We[k * 512 + m] * (T1[(128 + m) * 128 + n] + T2[m * 128 + n]);
    else if (y == 1)
      for (int m = 0; m < 128; ++m) s += We[k * 512 + 128 + m] * T1[m * 128 + n];
    else if (y == 2)
      for (int m = 0; m < 128; ++m) s += We[k * 512 + 256 + m] * T1[(256 + m) * 128 + n];
    else
      for (int m = 0; m < 128; ++m) s += We[k * 512 + 384 + m] * T2[(128 + m) * 128 + n];
    int kb = k >> 6, rl = k & 63;
    UTf[(size_t)y * 16384 + kb * 8192 + (n >> 4) * 1024 + (rl >> 5) * 512 +
        ((rl >> 3) & 3) * 128 + (n & 15) * 8 + (rl & 7)] = f2bf(s);
  } else if (idx < 66048) {
    int cid = idx - 65536, cv = cid >> 7, n = cid & 127;
    float s = 0.f;
    if (cv == 0) {
      for (int m = 0; m < 128; ++m)
        s += be[m] * (T1[(128 + m) * 128 + n] + T2[m * 128 + n]);
      for (int c = 0; c < 128; ++c) s += bs[c] * Wm[c * 128 + n];
      for (int c = 0; c < 128; ++c) s += bsame[c] * Wm[(128 + c) * 128 + n];
      s += bm_[n];
    } else if (cv == 1) {
      for (int m = 0; m < 128; ++m) s += be[128 + m] * T1[m * 128 + n];
    } else if (cv == 2) {
      for (int m = 0; m < 128; ++m) s += be[256 + m] * T1[(256 + m) * 128 + n];
    } else {
      for (int m = 0; m < 128; ++m) s += be[384 + m] * T2[(128 + m) * 128 + n];
    }
    cvec[cv * 128 + n] = s;
  }
}

// ---------------------------------------------------------------------------
// Encoder, all 4 y-GEMMs per block sharing one As staging (feat read 1x).
// B read directly from UTf (fragment order, L2-hot). y=0 -> out = origin+c0;
// y>=1 -> eT tiles in fragment order with the PERMUTED K-mapping:
// row ml (e-index m) -> tile q*4+(ml&3), rl = d*16 + (ml>>2).
__global__ __launch_bounds__(256) void k_enc(
    const float* __restrict__ feat, const ushort* __restrict__ UTf,
    const float* __restrict__ cvec, float* __restrict__ out,
    ushort* __restrict__ eT0, ushort* __restrict__ eT1, ushort* __restrict__ eT2) {
  __shared__ ushort As[64 * 136];
  __shared__ ushort stage[8192];
  const int t = threadIdx.x;
  const int gm0 = blockIdx.x * 64;
  const int b = gm0 >> 11, q = (gm0 >> 8) & 7, d = (gm0 >> 6) & 3;
  const int lane = t & 63, wave = t >> 6;
  const int m0w = (wave >> 1) * 32, n0w = (wave & 1) * 64;
  const int quad = lane >> 4, lr = lane & 15;
  const int jb = n0w >> 4;
  {  // stage A: fully coalesced f32 loads, convert, LDS
    const float4* src = (const float4*)(feat + (size_t)gm0 * 128);
#pragma unroll
    for (int p = 0; p < 8; ++p) {
      float4 f = src[p * 256 + t];
      int idx = p * 1024 + t * 4;
      int row = idx >> 7, col = idx & 127;
      ushort4 h4;
      h4.x = f2bf(f.x); h4.y = f2bf(f.y); h4.z = f2bf(f.z); h4.w = f2bf(f.w);
      *(ushort4*)&As[row * 136 + col] = h4;
    }
  }
  __syncthreads();

  for (int y = 0; y < 4; ++y) {
    f32x4 acc[2][4] = {};
    const ushort* By = UTf + (size_t)y * 16384;
#pragma unroll
    for (int kc = 0; kc < 4; ++kc) {
      bf16x8 a0 = *(const bf16x8*)&As[(m0w + lr) * 136 + kc * 32 + quad * 8];
      bf16x8 a1 = *(const bf16x8*)&As[(m0w + 16 + lr) * 136 + kc * 32 + quad * 8];
      const ushort* bp = By + (kc >> 1) * 8192 + (kc & 1) * 512 + quad * 128 + lr * 8;
      bf16x8 b0 = *(const bf16x8*)(bp + (jb + 0) * 1024);
      bf16x8 b1 = *(const bf16x8*)(bp + (jb + 1) * 1024);
      bf16x8 b2 = *(const bf16x8*)(bp + (jb + 2) * 1024);
      bf16x8 b3 = *(const bf16x8*)(bp + (jb + 3) * 1024);
      acc[0][0] = __builtin_amdgcn_mfma_f32_16x16x32_bf16(a0, b0, acc[0][0], 0, 0, 0);
      acc[0][1] = __builtin_amdgcn_mfma_f32_16x16x32_bf16(a0, b1, acc[0][1], 0, 0, 0);
      acc[0][2] = __builtin_amdgcn_mfma_f32_16x16x32_bf16(a0, b2, acc[0][2], 0, 0, 0);
      acc[0][3] = __builtin_amdgcn_mfma_f32_16x16x32_bf16(a0, b3, acc[0][3], 0, 0, 0);
      acc[1][0] = __builtin_amdgcn_mfma_f32_16x16x32_bf16(a1, b0, acc[1][0], 0, 0, 0);
      acc[1][1] = __builtin_amdgcn_mfma_f32_16x16x32_bf16(a1, b1, acc[1][1], 0, 0, 0);
      acc[1][2] = __builtin_amdgcn_mfma_f32_16x16x32_bf16(a1, b2, acc[1][2], 0, 0, 0);
      acc[1][3] = __builtin_amdgcn_mfma_f32_16x16x32_bf16(a1, b3, acc[1][3], 0, 0, 0);
    }
    if (y == 0) {
#pragma unroll
      for (int i = 0; i < 2; ++i)
#pragma unroll
        for (int j = 0; j < 4; ++j)
#pragma unroll
          for (int r = 0; r < 4; ++r) {
            int m = gm0 + m0w + i * 16 + quad * 4 + r;
            int n = n0w + j * 16 + lr;
            out[(size_t)m * 128 + n] = acc[i][j][r] + cvec[n];
          }
    } else {
      __syncthreads();  // prev copy (y-1) must finish reading stage
#pragma unroll
      for (int i = 0; i < 2; ++i)
#pragma unroll
        for (int j = 0; j < 4; ++j)
#pragma unroll
          for (int r = 0; r < 4; ++r) {
            int ml = m0w + i * 16 + quad * 4 + r;
            int n = n0w + j * 16 + lr;
            stage[(ml & 3) * 2048 + (n >> 4) * 256 + ((ml >> 5) & 1) * 128 +
                  (n & 15) * 8 + ((ml >> 2) & 7)] = f2bf(acc[i][j][r]);
          }
      __syncthreads();
      ushort* eTy = (y == 1) ? eT0 : (y == 2) ? eT1 : eT2;
      const int e_t = t >> 6, n2 = (t >> 3) & 7, tt = t & 7;
      ushort* dst = eTy + ((size_t)(b * 32 + q * 4 + e_t)) * 8192 + n2 * 1024 +
                    d * 256 + tt * 32;
      const ushort* src = stage + e_t * 2048 + n2 * 256 + tt * 32;
#pragma unroll
      for (int p = 0; p < 4; ++p)
        *(bf16x8*)(dst + p * 8) = *(const bf16x8*)(src + p * 8);
    }
  }
}

// ---------------------------------------------------------------------------
// Masked-mean GEMM from bitmaps (R5-proven). Bitmap staged to LDS; B-frags
// from L2 with depth-2 prefetch into statically-named register buffers
// (R4 lesson: dynamic register-array indexing -> scratch catastrophe).
__global__ __launch_bounds__(256, 3) void k_mm(
    const uint* __restrict__ bm, const ushort* __restrict__ eT0,
    const ushort* __restrict__ eT1, const ushort* __restrict__ eT2,
    const float* __restrict__ inv, const float* __restrict__ ind,
    const float* __restrict__ cvec, float* __restrict__ P0,
    float* __restrict__ P1, float* __restrict__ P2) {
  __shared__ uint sbm[64][68];
  const int t = threadIdx.x;
  const int id = blockIdx.x;
  const int xcd = id & 7, q = id >> 3;
  const int mtile = q & 31, gg = xcd * 3 + (q >> 5);
  const int b = gg & 7, mid = gg >> 3;
  const ushort* eT = (mid == 0) ? eT0 : (mid == 1) ? eT1 : eT2;
  float* Pm = (mid == 0) ? P0 : (mid == 1) ? P1 : P2;
  const float* cm = cvec + (mid + 1) * 128;
  const size_t rowbase = (size_t)b * 2048 + mtile * 64;
  const uint* bmbase = bm + ((size_t)mid * 16384 + rowbase) * 64;
  {  // stage 16KB bitmap
    int r = t >> 2, c0 = (t & 3) * 16;
    const uint* src = bmbase + (size_t)r * 64 + c0;
    uint4 v0 = *(const uint4*)src;
    uint4 v1 = *(const uint4*)(src + 4);
    uint4 v2 = *(const uint4*)(src + 8);
    uint4 v3 = *(const uint4*)(src + 12);
    *(uint4*)&sbm[r][c0] = v0;
    *(uint4*)&sbm[r][c0 + 4] = v1;
    *(uint4*)&sbm[r][c0 + 8] = v2;
    *(uint4*)&sbm[r][c0 + 12] = v3;
  }
  const int lane = t & 63, wave = t >> 6;
  const int m0w = (wave >> 1) * 32, n0w = (wave & 1) * 64;
  const int quad = lane >> 4, lr = lane & 15;
  const int jb = n0w >> 4;
  const int r0l = m0w + lr, r1l = r0l + 16;
  const ushort* bbase = eT + (size_t)b * 32 * 8192 + quad * 128 + lr * 8;
  f32x4 acc[2][4] = {};
  bf16x8 pb0[4], pb1[4];
#pragma unroll
  for (int j = 0; j < 4; ++j) {
    pb0[j] = *(const bf16x8*)(bbase + (jb + j) * 1024);
    pb1[j] = *(const bf16x8*)(bbase + 512 + (jb + j) * 1024);
  }
  __syncthreads();

#define MM_STEP(IT, PB)                                                       \
  do {                                                                        \
    const int it_ = (IT);                                                     \
    const uint w0 = sbm[r0l][it_];                                            \
    const uint w1 = sbm[r1l][it_];                                            \
    union { bf16x8 v; uint u[4]; } a0, a1;                                    \
    const uint s0 = w0 >> (quad * 8), s1 = w1 >> (quad * 8);                  \
    _Pragma("unroll")                                                         \
    for (int p = 0; p < 4; ++p) {                                             \
      a0.u[p] = (((s0 >> (2 * p)) & 1u) ? 0x3F80u : 0u) |                     \
                (((s0 >> (2 * p)) & 2u) ? 0x3F800000u : 0u);                  \
      a1.u[p] = (((s1 >> (2 * p)) & 1u) ? 0x3F80u : 0u) |                     \
                (((s1 >> (2 * p)) & 2u) ? 0x3F800000u : 0u);                  \
    }                                                                         \
    _Pragma("unroll")                                                         \
    for (int j = 0; j < 4; ++j) {                                             \
      acc[0][j] = __builtin_amdgcn_mfma_f32_16x16x32_bf16(a0.v, PB[j],        \
                                                          acc[0][j], 0, 0, 0);\
      acc[1][j] = __builtin_amdgcn_mfma_f32_16x16x32_bf16(a1.v, PB[j],        \
                                                          acc[1][j], 0, 0, 0);\
    }                                                                         \
    int itn_ = it_ + 2;                                                       \
    if (itn_ > 63) itn_ = 63;                                                 \
    const ushort* bp_ = bbase + (itn_ >> 1) * 8192 + (itn_ & 1) * 512;        \
    _Pragma("unroll")                                                         \
    for (int j = 0; j < 4; ++j)                                               \
      PB[j] = *(const bf16x8*)(bp_ + (jb + j) * 1024);                        \
  } while (0)

  for (int it2 = 0; it2 < 32; ++it2) {
    MM_STEP(2 * it2, pb0);
    MM_STEP(2 * it2 + 1, pb1);
  }
#undef MM_STEP

  float cmv[4];
#pragma unroll
  for (int j = 0; j < 4; ++j) cmv[j] = cm[n0w + j * 16 + lr];
#pragma unroll
  for (int i = 0; i < 2; ++i)
#pragma unroll
    for (int r = 0; r < 4; ++r) {
      const int ml = m0w + i * 16 + quad * 4 + r;
      const size_t row = rowbase + ml;
      const float iv = inv[(size_t)mid * 16384 + row];
      const float id_ = ind[(size_t)mid * 16384 + row];
#pragma unroll
      for (int j = 0; j < 4; ++j) {
        const int n = n0w + j * 16 + lr;
        Pm[row * 128 + n] = acc[i][j][r] * iv + id_ * cmv[j];
      }
    }
}

// ---------------------------------------------------------------------------
// Final merge: out(base) += P0 + P1 + P2. Pure streaming.
__global__ __launch_bounds__(256) void k_add(
    float4* __restrict__ out, const float4* __restrict__ P0,
    const float4* __restrict__ P1, const float4* __restrict__ P2) {
  const int i = blockIdx.x * 256 + threadIdx.x;  // 524288 float4s
  float4 o = out[i];
  const float4 a = P0[i], b = P1[i], c = P2[i];
  o.x += a.x + b.x + c.x;
  o.y += a.y + b.y + c.y;
  o.z += a.z + b.z + c.z;
  o.w += a.w + b.w + c.w;
  out[i] = o;
}

// ---------------------------------------------------------------------------
extern "C" void kernel_launch(void* const* d_in, const int* in_sizes, int n_in,
                              void* d_out, int out_size, void* d_ws,
                              size_t ws_size, hipStream_t stream) {
  const float* features = (const float*)d_in[0];
  const void* pred = d_in[1];
  const void* succ = d_in[2];
  const void* same = d_in[3];
  const float* W_enc = (const float*)d_in[4];
  const float* b_enc = (const float*)d_in[5];
  const float* W_space = (const float*)d_in[6];
  const float* b_space = (const float*)d_in[7];
  const float* W_same = (const float*)d_in[8];
  const float* b_same = (const float*)d_in[9];
  const float* W_mix = (const float*)d_in[10];
  const float* b_mix = (const float*)d_in[11];
  float* out = (float*)d_out;

  char* wsb = (char*)d_ws;
  ushort* UTf = (ushort*)wsb;                         // 128 KB (frag order)
  float* cvec = (float*)(wsb + 131072);               // 2 KB
  float* T1 = (float*)(wsb + 133120);                 // 192 KB
  float* T2 = (float*)(wsb + 329728);                 // 128 KB
  ushort* eT0 = (ushort*)(wsb + 460800);              // 4 MB each (frag order)
  ushort* eT1 = (ushort*)(wsb + 460800 + 4194304);
  ushort* eT2 = (ushort*)(wsb + 460800 + 8388608);
  uint* bm = (uint*)(wsb + 13043712);                 // 12 MB bitmaps (permuted)
  float* inv = (float*)(wsb + 25626624);              // 192 KB
  float* ind = (float*)(wsb + 25823232);              // 192 KB
  float* P0 = (float*)(wsb + 26019840);               // 8 MB each
  float* P1 = (float*)(wsb + 26019840 + 8388608);
  float* P2 = (float*)(wsb + 26019840 + 16777216);
  int* esz = (int*)(wsb + 51185664);

  hipMemsetAsync(esz, 1, 4, stream);
  k_detect<<<192, 256, 0, stream>>>((const uint*)pred, (const uint*)succ,
                                    (const uint*)same, esz);
  k_pack<<<12288, 256, 0, stream>>>(pred, succ, same, bm, inv, ind, esz);
  k_fuse1<<<320, 256, 0, stream>>>(W_space, W_same, W_mix, T1, T2);
  k_fuse2<<<258, 256, 0, stream>>>(W_enc, b_enc, b_space, b_same, b_mix, W_mix,
                                   T1, T2, UTf, cvec);
  k_enc<<<256, 256, 0, stream>>>(features, UTf, cvec, out, eT0, eT1, eT2);
  k_mm<<<768, 256, 0, stream>>>(bm, eT0, eT1, eT2, inv, ind, cvec, P0, P1, P2);
  k_add<<<2048, 256, 0, stream>>>((float4*)out, (const float4*)P0,
                                  (const float4*)P1, (const float4*)P2);
}